// Round 11
// baseline (408.228 us; speedup 1.0000x reference)
//
#include <hip/hip_runtime.h>

// RelGCN round 11: whole-wave-row staging (1KB-contiguous per VMEM inst, DRAM
// page-friendly) + bf16 adj caching (gemm1 stores f2bf(adj) to ws; gemm2 reads
// half the bytes). MFMA operands bit-identical to round 10.
//   prep    : hbf[r] = bf16(in @ W[r] + b[r])  fragment-swizzled  (verified)
//   gemm<0> : out = tanh(sum adj_f32 @ hbf); converts+streams adj -> adjbf (nt)
//   gemm<1> : out = tanh(sum adjbf  @ hbf);  reads bf16 adj (403MB not 805MB)
//   Pipeline per tile (write-early, 1 barrier): B-loads | commit A(t+1) to LDS
//   (+store adjbf in PASS0) | gload A(t+2) | 16 MFMA | barrier.

#define NN 8192
#define AS 520  // LDS A-tile row stride in SHORTS (520*2B=1040B: 16B-aligned, 2-way banks)

typedef __attribute__((ext_vector_type(4))) float float4v;
typedef __attribute__((ext_vector_type(8))) short short8v;
typedef __attribute__((ext_vector_type(4))) short short4v;

__device__ inline unsigned short f2bf(float f) {
  unsigned int u = __builtin_bit_cast(unsigned int, f);
  return (unsigned short)((u + 0x7FFFu + ((u >> 16) & 1u)) >> 16);  // RNE
}

// grid = 3*1024; hbf[((r*1024 + m/8)*64 + j)*8 + (m&7)] = bf16(h[r][m][j])
__global__ __launch_bounds__(256) void prep(
    const float* __restrict__ in, const float* __restrict__ W,
    const float* __restrict__ b, unsigned short* __restrict__ hbf) {
  __shared__ float Ws[64 * 64];
  __shared__ float xs[8 * 64];
  const int tid = threadIdx.x;
  const int r = blockIdx.x >> 10;
  const int kb = blockIdx.x & 1023;
#pragma unroll
  for (int i = 0; i < 16; ++i) Ws[tid + i * 256] = W[r * 4096 + tid + i * 256];
  xs[tid] = in[(size_t)kb * 512 + tid];
  xs[tid + 256] = in[(size_t)kb * 512 + 256 + tid];
  __syncthreads();
#pragma unroll
  for (int idx = tid; idx < 512; idx += 256) {
    const int ml = idx >> 6;
    const int j = idx & 63;
    float acc = b[r * 64 + j];
#pragma unroll
    for (int f = 0; f < 64; ++f) acc += xs[ml * 64 + f] * Ws[f * 64 + j];
    hbf[((size_t)((r * 1024 + kb) * 64 + j)) * 8 + ml] = f2bf(acc);
  }
}

// tile T (0..47): relation = T>>4, k0-within-relation = (T&15)*512 (elements)
#define TOFF(T) ((((size_t)((T) >> 4)) << 26) + ((size_t)((T) & 15) << 9))

// PASS 0: A from adj (f32), convert in staging path, stream adjbf (nt stores).
// PASS 1: A from adjbf (bf16).
template <int PASS>
__global__ __launch_bounds__(256) void gemm_mfma(
    const float* __restrict__ adj, unsigned short* __restrict__ adjbf,
    const unsigned short* __restrict__ hbf, float* __restrict__ out) {
  __shared__ unsigned short lds[2 * 16 * AS];  // two 16x512 bf16 A tiles, 33.3KB
  unsigned short* buf0 = lds;
  unsigned short* buf1 = lds + 16 * AS;
  const int tid = threadIdx.x;
  const int w = tid >> 6;       // wave 0..3; stages rows w*4..w*4+3
  const int l = tid & 63;
  const int lrow = l & 15;
  const int lk = l >> 4;
  const int mb = blockIdx.x;

  const float* af32 = adj + (size_t)(mb * 16 + w * 4) * NN;          // f32 elems
  unsigned short* abf = adjbf + (size_t)(mb * 16 + w * 4) * NN;      // bf16 elems

  float4v acc0 = {0.f, 0.f, 0.f, 0.f}, acc1 = acc0, acc2 = acc0, acc3 = acc0;
  float4v Pf[8], Qf[8];   // PASS0 slots: (rr 0..3) x (half 0..1), 1KB/inst/row
  short8v Ps[4], Qs[4];   // PASS1 slots: rr 0..3, 1KB-bf16/inst/row

#define GLOAD(T, SLF, SLS)                                                     \
  do {                                                                         \
    if constexpr (PASS == 0) {                                                 \
      _Pragma("unroll") for (int i = 0; i < 8; ++i) {                          \
        const int rr_ = i >> 1, hh_ = i & 1;                                   \
        SLF[i] = __builtin_nontemporal_load(                                   \
            (const float4v*)(af32 + (size_t)rr_ * NN + TOFF(T) + hh_ * 256 +   \
                             l * 4));                                          \
      }                                                                        \
    } else {                                                                   \
      _Pragma("unroll") for (int rr_ = 0; rr_ < 4; ++rr_) {                    \
        SLS[rr_] = __builtin_nontemporal_load(                                 \
            (const short8v*)(abf + (size_t)rr_ * NN + TOFF(T) + l * 8));       \
      }                                                                        \
    }                                                                          \
  } while (0)

#define COMMIT(BUF, T, SLF, SLS)                                               \
  do {                                                                         \
    if constexpr (PASS == 0) {                                                 \
      _Pragma("unroll") for (int i = 0; i < 8; ++i) {                          \
        const int rr_ = i >> 1, hh_ = i & 1;                                   \
        short4v c_;                                                            \
        c_[0] = (short)f2bf(SLF[i][0]); c_[1] = (short)f2bf(SLF[i][1]);        \
        c_[2] = (short)f2bf(SLF[i][2]); c_[3] = (short)f2bf(SLF[i][3]);        \
        *(short4v*)&(BUF)[(w * 4 + rr_) * AS + hh_ * 256 + l * 4] = c_;        \
        __builtin_nontemporal_store(                                           \
            c_, (short4v*)(abf + (size_t)rr_ * NN + TOFF(T) + hh_ * 256 +      \
                           l * 4));                                            \
      }                                                                        \
    } else {                                                                   \
      _Pragma("unroll") for (int rr_ = 0; rr_ < 4; ++rr_) {                    \
        *(short8v*)&(BUF)[(w * 4 + rr_) * AS + l * 8] = SLS[rr_];              \
      }                                                                        \
    }                                                                          \
  } while (0)

#define DO_CHUNK(CUR, CC, B0, B1, B2, B3)                                      \
  do {                                                                         \
    const short8v av_ =                                                        \
        *(const short8v*)&(CUR)[lrow * AS + (w * 4 + (CC)) * 32 + lk * 8];     \
    acc0 = __builtin_amdgcn_mfma_f32_16x16x32_bf16(av_, B0, acc0, 0, 0, 0);    \
    acc1 = __builtin_amdgcn_mfma_f32_16x16x32_bf16(av_, B1, acc1, 0, 0, 0);    \
    acc2 = __builtin_amdgcn_mfma_f32_16x16x32_bf16(av_, B2, acc2, 0, 0, 0);    \
    acc3 = __builtin_amdgcn_mfma_f32_16x16x32_bf16(av_, B3, acc3, 0, 0, 0);    \
  } while (0)

#define TILE(T, CBUF, WBUF, WSF, WSS, LSF, LSS)                                \
  do {                                                                         \
    const int rr_ = (T) >> 4;                                                  \
    const unsigned short* pbb_ =                                               \
        hbf + ((size_t)(rr_ * 1024 + ((T) & 15) * 64 + w * 16 + lk) * 512) +   \
        lrow * 8;                                                              \
    const short8v B00 = *(const short8v*)(pbb_);                               \
    const short8v B01 = *(const short8v*)(pbb_ + 128);                         \
    const short8v B02 = *(const short8v*)(pbb_ + 256);                         \
    const short8v B03 = *(const short8v*)(pbb_ + 384);                         \
    const short8v B10 = *(const short8v*)(pbb_ + 2048);                        \
    const short8v B11 = *(const short8v*)(pbb_ + 2176);                        \
    const short8v B12 = *(const short8v*)(pbb_ + 2304);                        \
    const short8v B13 = *(const short8v*)(pbb_ + 2432);                        \
    const short8v B20 = *(const short8v*)(pbb_ + 4096);                        \
    const short8v B21 = *(const short8v*)(pbb_ + 4224);                        \
    const short8v B22 = *(const short8v*)(pbb_ + 4352);                        \
    const short8v B23 = *(const short8v*)(pbb_ + 4480);                        \
    const short8v B30 = *(const short8v*)(pbb_ + 6144);                        \
    const short8v B31 = *(const short8v*)(pbb_ + 6272);                        \
    const short8v B32 = *(const short8v*)(pbb_ + 6400);                        \
    const short8v B33 = *(const short8v*)(pbb_ + 6528);                        \
    if ((T) + 1 < 48) COMMIT(WBUF, (T) + 1, WSF, WSS);                         \
    if ((T) + 2 < 48) GLOAD((T) + 2, LSF, LSS);                                \
    DO_CHUNK(CBUF, 0, B00, B01, B02, B03);                                     \
    DO_CHUNK(CBUF, 1, B10, B11, B12, B13);                                     \
    DO_CHUNK(CBUF, 2, B20, B21, B22, B23);                                     \
    DO_CHUNK(CBUF, 3, B30, B31, B32, B33);                                     \
    __syncthreads();                                                           \
  } while (0)

  // prologue: A(0) -> buf0 (+store), A(1) held in Q
  GLOAD(0, Pf, Ps);
  COMMIT(buf0, 0, Pf, Ps);
  GLOAD(1, Qf, Qs);
  __syncthreads();

#pragma unroll 1
  for (int tt = 0; tt < 48; tt += 2) {
    TILE(tt, buf0, buf1, Qf, Qs, Pf, Ps);
    TILE(tt + 1, buf1, buf0, Pf, Ps, Qf, Qs);
  }
#undef TILE
#undef DO_CHUNK
#undef COMMIT
#undef GLOAD

  // cross-wave reduce + tanh (red aliases lds; compute done, barrier passed)
  float* red = (float*)lds;
#pragma unroll
  for (int q = 0; q < 4; ++q) {
    red[w * 1024 + (lk * 4 + q) * 64 + 0 + lrow] = acc0[q];
    red[w * 1024 + (lk * 4 + q) * 64 + 16 + lrow] = acc1[q];
    red[w * 1024 + (lk * 4 + q) * 64 + 32 + lrow] = acc2[q];
    red[w * 1024 + (lk * 4 + q) * 64 + 48 + lrow] = acc3[q];
  }
  __syncthreads();
#pragma unroll
  for (int idx = tid; idx < 1024; idx += 256) {
    const float s = red[idx] + red[1024 + idx] + red[2048 + idx] + red[3072 + idx];
    out[(size_t)mb * 1024 + idx] = tanhf(s);
  }
}

__global__ __launch_bounds__(256) void fill_sentinel(float* __restrict__ dst) {
  dst[blockIdx.x * 256 + threadIdx.x] = 7.0f;
}

extern "C" void kernel_launch(void* const* d_in, const int* in_sizes, int n_in,
                              void* d_out, int out_size, void* d_ws, size_t ws_size,
                              hipStream_t stream) {
  const float* x   = (const float*)d_in[0];
  const float* adj = (const float*)d_in[1];
  const float* W1  = (const float*)d_in[2];
  const float* b1  = (const float*)d_in[3];
  const float* W2  = (const float*)d_in[4];
  const float* b2  = (const float*)d_in[5];
  float* out = (float*)d_out;

  const size_t HBF_B   = (size_t)3 * 8192 * 64 * 2;     // 3 MB
  const size_t T_B     = (size_t)8192 * 64 * 4;         // 2 MB
  const size_t ADJBF_B = (size_t)3 * 8192 * 8192 * 2;   // 403 MB
  if (ws_size < HBF_B + T_B + ADJBF_B) {
    fill_sentinel<<<2048, 256, 0, stream>>>(out);
    return;
  }
  unsigned short* hbf   = (unsigned short*)d_ws;
  float* t              = (float*)((char*)d_ws + HBF_B);
  unsigned short* adjbf = (unsigned short*)((char*)d_ws + HBF_B + T_B);

  // layer 1: reads f32 adj, caches bf16 adj
  prep<<<3 * 1024, 256, 0, stream>>>(x, W1, b1, hbf);
  gemm_mfma<0><<<512, 256, 0, stream>>>(adj, adjbf, hbf, t);
  // layer 2: reads bf16 adj (half the bytes)
  prep<<<3 * 1024, 256, 0, stream>>>(t, W2, b2, hbf);
  gemm_mfma<1><<<512, 256, 0, stream>>>(adj, adjbf, hbf, out);
}

// Round 12
// 358.981 us; speedup vs baseline: 1.1372x; 1.1372x over previous
//
#include <hip/hip_runtime.h>

// RelGCN round 12: r10 verbatim + per-block k-phase rotation (channel spread).
// Every block starts its 48-tile k-loop at tile (mb*29)%48 and wraps, so the
// ~8192 concurrent row-streams are phase-distributed across the 32KB row
// period -> uniform HBM channel load (lockstep-k congruence was the surviving
// theory for the 4.9 vs 6.6 TB/s gap).
//   prep : hbf[r] = bf16(in @ W[r] + b[r])  fragment-swizzled   (verified)
//   gemm : out = tanh( sum_{r,k} adj[r] @ hbf[r] )   [f32 out]
//          grid 512 x 4 waves, 16 rows/block, 48 tiles of 512-k, write-early
//          LDS double buffer, 1 barrier/tile, nontemporal adj loads.

#define NN 8192
#define TS 516  // LDS row stride (floats): 512 + 4 (16B-aligned, bank-spread)

typedef __attribute__((ext_vector_type(4))) float float4v;
typedef __attribute__((ext_vector_type(8))) short short8v;

__device__ inline unsigned short f2bf(float f) {
  unsigned int u = __builtin_bit_cast(unsigned int, f);
  return (unsigned short)((u + 0x7FFFu + ((u >> 16) & 1u)) >> 16);  // RNE
}

// grid = 3*1024; hbf[((r*1024 + m/8)*64 + j)*8 + (m&7)] = bf16(h[r][m][j])
__global__ __launch_bounds__(256) void prep(
    const float* __restrict__ in, const float* __restrict__ W,
    const float* __restrict__ b, unsigned short* __restrict__ hbf) {
  __shared__ float Ws[64 * 64];
  __shared__ float xs[8 * 64];
  const int tid = threadIdx.x;
  const int r = blockIdx.x >> 10;
  const int kb = blockIdx.x & 1023;
#pragma unroll
  for (int i = 0; i < 16; ++i) Ws[tid + i * 256] = W[r * 4096 + tid + i * 256];
  xs[tid] = in[(size_t)kb * 512 + tid];
  xs[tid + 256] = in[(size_t)kb * 512 + 256 + tid];
  __syncthreads();
#pragma unroll
  for (int idx = tid; idx < 512; idx += 256) {
    const int ml = idx >> 6;
    const int j = idx & 63;
    float acc = b[r * 64 + j];
#pragma unroll
    for (int f = 0; f < 64; ++f) acc += xs[ml * 64 + f] * Ws[f * 64 + j];
    hbf[((size_t)((r * 1024 + kb) * 64 + j)) * 8 + ml] = f2bf(acc);
  }
}

__global__ __launch_bounds__(256) void gemm_mfma(
    const float* __restrict__ adj, const unsigned short* __restrict__ hbf,
    float* __restrict__ out) {
  __shared__ float lds[2 * 16 * TS];  // 66 KB: two 16x512 A tiles
  float* buf0 = lds;
  float* buf1 = lds + 16 * TS;
  const int tid = threadIdx.x;
  const int w = tid >> 6;
  const int l = tid & 63;
  const int lrow = l & 15;
  const int lk = l >> 4;
  const int mb = blockIdx.x;
  const int phase = (mb * 29) % 48;  // k-phase rotation (29 coprime to 48)

  // staging map: thread -> (row, 16B seg); instr i covers 16 rows x 256B runs
  const int srow = tid >> 4;
  const int sseg = tid & 15;
  const float* arow = adj + (size_t)(mb * 16 + srow) * NN + sseg * 4;

  float4v acc0 = {0.f, 0.f, 0.f, 0.f}, acc1 = acc0, acc2 = acc0, acc3 = acc0;
  float4v P0, P1, P2, P3, P4, P5, P6, P7, Q0, Q1, Q2, Q3, Q4, Q5, Q6, Q7;

// wrap loop-counter TQ into actual tile id
#define TW(TQ) ((TQ) + phase >= 48 ? (TQ) + phase - 48 : (TQ) + phase)
// tile T (0..47): r = T>>4, within-rel k0 = (T&15)*512
#define TOFF(T) (((size_t)((T) >> 4) << 26) + ((size_t)((T) & 15) << 9))

#define GLOAD(T, S)                                                            \
  do {                                                                         \
    const float* pa_ = arow + TOFF(T);                                         \
    S##0 = __builtin_nontemporal_load((const float4v*)(pa_));                  \
    S##1 = __builtin_nontemporal_load((const float4v*)(pa_ + 64));             \
    S##2 = __builtin_nontemporal_load((const float4v*)(pa_ + 128));            \
    S##3 = __builtin_nontemporal_load((const float4v*)(pa_ + 192));            \
    S##4 = __builtin_nontemporal_load((const float4v*)(pa_ + 256));            \
    S##5 = __builtin_nontemporal_load((const float4v*)(pa_ + 320));            \
    S##6 = __builtin_nontemporal_load((const float4v*)(pa_ + 384));            \
    S##7 = __builtin_nontemporal_load((const float4v*)(pa_ + 448));            \
  } while (0)

#define DSWRITE(BUF, S)                                                        \
  do {                                                                         \
    float* p_ = (BUF) + srow * TS + sseg * 4;                                  \
    *(float4v*)(p_) = S##0;                                                    \
    *(float4v*)(p_ + 64) = S##1;                                               \
    *(float4v*)(p_ + 128) = S##2;                                              \
    *(float4v*)(p_ + 192) = S##3;                                              \
    *(float4v*)(p_ + 256) = S##4;                                              \
    *(float4v*)(p_ + 320) = S##5;                                              \
    *(float4v*)(p_ + 384) = S##6;                                              \
    *(float4v*)(p_ + 448) = S##7;                                              \
  } while (0)

#define DO_CHUNK(CUR, CC, B0, B1, B2, B3)                                      \
  do {                                                                         \
    const float* ap_ = (CUR) + lrow * TS + (w * 4 + (CC)) * 32 + lk * 8;       \
    const float4v a0_ = *(const float4v*)ap_;                                  \
    const float4v a1_ = *(const float4v*)(ap_ + 4);                            \
    short8v av_;                                                               \
    av_[0] = (short)f2bf(a0_[0]); av_[1] = (short)f2bf(a0_[1]);                \
    av_[2] = (short)f2bf(a0_[2]); av_[3] = (short)f2bf(a0_[3]);                \
    av_[4] = (short)f2bf(a1_[0]); av_[5] = (short)f2bf(a1_[1]);                \
    av_[6] = (short)f2bf(a1_[2]); av_[7] = (short)f2bf(a1_[3]);                \
    acc0 = __builtin_amdgcn_mfma_f32_16x16x32_bf16(av_, B0, acc0, 0, 0, 0);    \
    acc1 = __builtin_amdgcn_mfma_f32_16x16x32_bf16(av_, B1, acc1, 0, 0, 0);    \
    acc2 = __builtin_amdgcn_mfma_f32_16x16x32_bf16(av_, B2, acc2, 0, 0, 0);    \
    acc3 = __builtin_amdgcn_mfma_f32_16x16x32_bf16(av_, B3, acc3, 0, 0, 0);    \
  } while (0)

// wave w handles chunks w*4..w*4+3 of the 16 chunks (32-k each) in the tile.
// TQ = loop counter (pipeline position), T_ = rotated tile id (memory address).
#define TILE(TQ, CBUF, WBUF, WS, LS)                                           \
  do {                                                                         \
    const int T_ = TW(TQ);                                                     \
    const unsigned short* pbb_ =                                               \
        hbf +                                                                  \
        ((size_t)((T_ >> 4) * 1024 + (T_ & 15) * 64 + w * 16 + lk) * 512) +    \
        lrow * 8;                                                              \
    const short8v B00 = *(const short8v*)(pbb_);                               \
    const short8v B01 = *(const short8v*)(pbb_ + 128);                         \
    const short8v B02 = *(const short8v*)(pbb_ + 256);                         \
    const short8v B03 = *(const short8v*)(pbb_ + 384);                         \
    const short8v B10 = *(const short8v*)(pbb_ + 2048);                        \
    const short8v B11 = *(const short8v*)(pbb_ + 2176);                        \
    const short8v B12 = *(const short8v*)(pbb_ + 2304);                        \
    const short8v B13 = *(const short8v*)(pbb_ + 2432);                        \
    const short8v B20 = *(const short8v*)(pbb_ + 4096);                        \
    const short8v B21 = *(const short8v*)(pbb_ + 4224);                        \
    const short8v B22 = *(const short8v*)(pbb_ + 4352);                        \
    const short8v B23 = *(const short8v*)(pbb_ + 4480);                        \
    const short8v B30 = *(const short8v*)(pbb_ + 6144);                        \
    const short8v B31 = *(const short8v*)(pbb_ + 6272);                        \
    const short8v B32 = *(const short8v*)(pbb_ + 6400);                        \
    const short8v B33 = *(const short8v*)(pbb_ + 6528);                        \
    if ((TQ) + 1 < 48) DSWRITE(WBUF, WS);                                      \
    if ((TQ) + 2 < 48) GLOAD(TW((TQ) + 2), LS);                                \
    DO_CHUNK(CBUF, 0, B00, B01, B02, B03);                                     \
    DO_CHUNK(CBUF, 1, B10, B11, B12, B13);                                     \
    DO_CHUNK(CBUF, 2, B20, B21, B22, B23);                                     \
    DO_CHUNK(CBUF, 3, B30, B31, B32, B33);                                     \
    __syncthreads();                                                           \
  } while (0)

  // prologue: A(tile TW(0)) -> buf0, A(TW(1)) held in Q
  GLOAD(TW(0), P);
  DSWRITE(buf0, P);
  GLOAD(TW(1), Q);
  __syncthreads();

#pragma unroll 1
  for (int tq = 0; tq < 48; tq += 2) {
    TILE(tq, buf0, buf1, Q, P);      // even: compute buf0, commit A(tq+1), load A(tq+2)->P
    TILE(tq + 1, buf1, buf0, P, Q);  // odd : compute buf1, commit A(tq+2), load A(tq+3)->Q
  }
#undef TILE
#undef DO_CHUNK
#undef DSWRITE
#undef GLOAD
#undef TOFF
#undef TW

  // cross-wave reduce + tanh (red aliases lds; compute is done)
  float* red = lds;
#pragma unroll
  for (int q = 0; q < 4; ++q) {
    red[w * 1024 + (lk * 4 + q) * 64 + 0 + lrow] = acc0[q];
    red[w * 1024 + (lk * 4 + q) * 64 + 16 + lrow] = acc1[q];
    red[w * 1024 + (lk * 4 + q) * 64 + 32 + lrow] = acc2[q];
    red[w * 1024 + (lk * 4 + q) * 64 + 48 + lrow] = acc3[q];
  }
  __syncthreads();
#pragma unroll
  for (int idx = tid; idx < 1024; idx += 256) {
    const float s = red[idx] + red[1024 + idx] + red[2048 + idx] + red[3072 + idx];
    out[(size_t)mb * 1024 + idx] = tanhf(s);
  }
}

__global__ __launch_bounds__(256) void fill_sentinel(float* __restrict__ dst) {
  dst[blockIdx.x * 256 + threadIdx.x] = 7.0f;
}

extern "C" void kernel_launch(void* const* d_in, const int* in_sizes, int n_in,
                              void* d_out, int out_size, void* d_ws, size_t ws_size,
                              hipStream_t stream) {
  const float* x   = (const float*)d_in[0];
  const float* adj = (const float*)d_in[1];
  const float* W1  = (const float*)d_in[2];
  const float* b1  = (const float*)d_in[3];
  const float* W2  = (const float*)d_in[4];
  const float* b2  = (const float*)d_in[5];
  float* out = (float*)d_out;

  const size_t HBF_B = (size_t)3 * 8192 * 64 * 2;  // 3 MB
  const size_t T_B   = (size_t)8192 * 64 * 4;      // 2 MB
  if (ws_size < HBF_B + T_B) {
    fill_sentinel<<<2048, 256, 0, stream>>>(out);
    return;
  }
  unsigned short* hbf = (unsigned short*)d_ws;
  float* t = (float*)((char*)d_ws + HBF_B);

  // layer 1
  prep<<<3 * 1024, 256, 0, stream>>>(x, W1, b1, hbf);
  gemm_mfma<<<512, 256, 0, stream>>>(adj, hbf, t);
  // layer 2
  prep<<<3 * 1024, 256, 0, stream>>>(t, W2, b2, hbf);
  gemm_mfma<<<512, 256, 0, stream>>>(adj, hbf, out);
}

// Round 13
// 347.041 us; speedup vs baseline: 1.1763x; 1.0344x over previous
//
#include <hip/hip_runtime.h>

// RelGCN round 13: gemm = r12 VERBATIM (k-phase rotation, write-early dbuf).
// prep rewritten: 3x256 grid (32 rows/block), x-row in VGPRs, W read as
// broadcast float4 from LDS (8 lanes/address -> conflict-free), 8 outs/thread.
// FMA order per output unchanged (f ascending) -> bit-identical hbf.

#define NN 8192
#define TS 516  // LDS row stride (floats): 512 + 4 (16B-aligned, bank-spread)

typedef __attribute__((ext_vector_type(4))) float float4v;
typedef __attribute__((ext_vector_type(8))) short short8v;

__device__ inline unsigned short f2bf(float f) {
  unsigned int u = __builtin_bit_cast(unsigned int, f);
  return (unsigned short)((u + 0x7FFFu + ((u >> 16) & 1u)) >> 16);  // RNE
}

// grid = 3*256: r = bid>>8, g = bid&255 -> rows m = g*32 .. +31.
// hbf[((r*1024 + m/8)*64 + j)*8 + (m&7)] = bf16(b[r][j] + sum_f in[m][f] W[r][f][j])
__global__ __launch_bounds__(256) void prep(
    const float* __restrict__ in, const float* __restrict__ W,
    const float* __restrict__ b, unsigned short* __restrict__ hbf) {
  __shared__ float Ws[64 * 64];  // natural [f][j]
  const int tid = threadIdx.x;
  const int r = blockIdx.x >> 8;
  const int g = blockIdx.x & 255;
  const int ml = tid >> 3;        // 0..31
  const int j0 = (tid & 7) * 8;   // 0..56
  const int m = g * 32 + ml;

#pragma unroll
  for (int i = 0; i < 16; ++i) Ws[tid + i * 256] = W[r * 4096 + tid + i * 256];

  float4v xr[16];
#pragma unroll
  for (int i = 0; i < 16; ++i)
    xr[i] = *(const float4v*)&in[(size_t)m * 64 + i * 4];

  float acc[8];
  {
    const float4v b0 = *(const float4v*)&b[r * 64 + j0];
    const float4v b1 = *(const float4v*)&b[r * 64 + j0 + 4];
#pragma unroll
    for (int jj = 0; jj < 4; ++jj) { acc[jj] = b0[jj]; acc[jj + 4] = b1[jj]; }
  }
  __syncthreads();

#pragma unroll
  for (int fi = 0; fi < 16; ++fi) {
    const float4v xv = xr[fi];
#pragma unroll
    for (int df = 0; df < 4; ++df) {
      const int f = fi * 4 + df;
      const float a = xv[df];
      const float4v w0 = *(const float4v*)&Ws[f * 64 + j0];      // broadcast (8 lanes/addr)
      const float4v w1 = *(const float4v*)&Ws[f * 64 + j0 + 4];
#pragma unroll
      for (int jj = 0; jj < 4; ++jj) {
        acc[jj] += a * w0[jj];
        acc[jj + 4] += a * w1[jj];
      }
    }
  }

  const size_t base = ((size_t)(r * 1024 + (m >> 3)) * 64) * 8 + (m & 7);
#pragma unroll
  for (int jj = 0; jj < 8; ++jj)
    hbf[base + (size_t)(j0 + jj) * 8] = f2bf(acc[jj]);
}

__global__ __launch_bounds__(256) void gemm_mfma(
    const float* __restrict__ adj, const unsigned short* __restrict__ hbf,
    float* __restrict__ out) {
  __shared__ float lds[2 * 16 * TS];  // 66 KB: two 16x512 A tiles
  float* buf0 = lds;
  float* buf1 = lds + 16 * TS;
  const int tid = threadIdx.x;
  const int w = tid >> 6;
  const int l = tid & 63;
  const int lrow = l & 15;
  const int lk = l >> 4;
  const int mb = blockIdx.x;
  const int phase = (mb * 29) % 48;  // k-phase rotation (29 coprime to 48)

  // staging map: thread -> (row, 16B seg); instr i covers 16 rows x 256B runs
  const int srow = tid >> 4;
  const int sseg = tid & 15;
  const float* arow = adj + (size_t)(mb * 16 + srow) * NN + sseg * 4;

  float4v acc0 = {0.f, 0.f, 0.f, 0.f}, acc1 = acc0, acc2 = acc0, acc3 = acc0;
  float4v P0, P1, P2, P3, P4, P5, P6, P7, Q0, Q1, Q2, Q3, Q4, Q5, Q6, Q7;

// wrap loop-counter TQ into actual tile id
#define TW(TQ) ((TQ) + phase >= 48 ? (TQ) + phase - 48 : (TQ) + phase)
// tile T (0..47): r = T>>4, within-rel k0 = (T&15)*512
#define TOFF(T) (((size_t)((T) >> 4) << 26) + ((size_t)((T) & 15) << 9))

#define GLOAD(T, S)                                                            \
  do {                                                                         \
    const float* pa_ = arow + TOFF(T);                                         \
    S##0 = __builtin_nontemporal_load((const float4v*)(pa_));                  \
    S##1 = __builtin_nontemporal_load((const float4v*)(pa_ + 64));             \
    S##2 = __builtin_nontemporal_load((const float4v*)(pa_ + 128));            \
    S##3 = __builtin_nontemporal_load((const float4v*)(pa_ + 192));            \
    S##4 = __builtin_nontemporal_load((const float4v*)(pa_ + 256));            \
    S##5 = __builtin_nontemporal_load((const float4v*)(pa_ + 320));            \
    S##6 = __builtin_nontemporal_load((const float4v*)(pa_ + 384));            \
    S##7 = __builtin_nontemporal_load((const float4v*)(pa_ + 448));            \
  } while (0)

#define DSWRITE(BUF, S)                                                        \
  do {                                                                         \
    float* p_ = (BUF) + srow * TS + sseg * 4;                                  \
    *(float4v*)(p_) = S##0;                                                    \
    *(float4v*)(p_ + 64) = S##1;                                               \
    *(float4v*)(p_ + 128) = S##2;                                              \
    *(float4v*)(p_ + 192) = S##3;                                              \
    *(float4v*)(p_ + 256) = S##4;                                              \
    *(float4v*)(p_ + 320) = S##5;                                              \
    *(float4v*)(p_ + 384) = S##6;                                              \
    *(float4v*)(p_ + 448) = S##7;                                              \
  } while (0)

#define DO_CHUNK(CUR, CC, B0, B1, B2, B3)                                      \
  do {                                                                         \
    const float* ap_ = (CUR) + lrow * TS + (w * 4 + (CC)) * 32 + lk * 8;       \
    const float4v a0_ = *(const float4v*)ap_;                                  \
    const float4v a1_ = *(const float4v*)(ap_ + 4);                            \
    short8v av_;                                                               \
    av_[0] = (short)f2bf(a0_[0]); av_[1] = (short)f2bf(a0_[1]);                \
    av_[2] = (short)f2bf(a0_[2]); av_[3] = (short)f2bf(a0_[3]);                \
    av_[4] = (short)f2bf(a1_[0]); av_[5] = (short)f2bf(a1_[1]);                \
    av_[6] = (short)f2bf(a1_[2]); av_[7] = (short)f2bf(a1_[3]);                \
    acc0 = __builtin_amdgcn_mfma_f32_16x16x32_bf16(av_, B0, acc0, 0, 0, 0);    \
    acc1 = __builtin_amdgcn_mfma_f32_16x16x32_bf16(av_, B1, acc1, 0, 0, 0);    \
    acc2 = __builtin_amdgcn_mfma_f32_16x16x32_bf16(av_, B2, acc2, 0, 0, 0);    \
    acc3 = __builtin_amdgcn_mfma_f32_16x16x32_bf16(av_, B3, acc3, 0, 0, 0);    \
  } while (0)

// wave w handles chunks w*4..w*4+3 of the 16 chunks (32-k each) in the tile.
// TQ = loop counter (pipeline position), T_ = rotated tile id (memory address).
#define TILE(TQ, CBUF, WBUF, WS, LS)                                           \
  do {                                                                         \
    const int T_ = TW(TQ);                                                     \
    const unsigned short* pbb_ =                                               \
        hbf +                                                                  \
        ((size_t)((T_ >> 4) * 1024 + (T_ & 15) * 64 + w * 16 + lk) * 512) +    \
        lrow * 8;                                                              \
    const short8v B00 = *(const short8v*)(pbb_);                               \
    const short8v B01 = *(const short8v*)(pbb_ + 128);                         \
    const short8v B02 = *(const short8v*)(pbb_ + 256);                         \
    const short8v B03 = *(const short8v*)(pbb_ + 384);                         \
    const short8v B10 = *(const short8v*)(pbb_ + 2048);                        \
    const short8v B11 = *(const short8v*)(pbb_ + 2176);                        \
    const short8v B12 = *(const short8v*)(pbb_ + 2304);                        \
    const short8v B13 = *(const short8v*)(pbb_ + 2432);                        \
    const short8v B20 = *(const short8v*)(pbb_ + 4096);                        \
    const short8v B21 = *(const short8v*)(pbb_ + 4224);                        \
    const short8v B22 = *(const short8v*)(pbb_ + 4352);                        \
    const short8v B23 = *(const short8v*)(pbb_ + 4480);                        \
    const short8v B30 = *(const short8v*)(pbb_ + 6144);                        \
    const short8v B31 = *(const short8v*)(pbb_ + 6272);                        \
    const short8v B32 = *(const short8v*)(pbb_ + 6400);                        \
    const short8v B33 = *(const short8v*)(pbb_ + 6528);                        \
    if ((TQ) + 1 < 48) DSWRITE(WBUF, WS);                                      \
    if ((TQ) + 2 < 48) GLOAD(TW((TQ) + 2), LS);                                \
    DO_CHUNK(CBUF, 0, B00, B01, B02, B03);                                     \
    DO_CHUNK(CBUF, 1, B10, B11, B12, B13);                                     \
    DO_CHUNK(CBUF, 2, B20, B21, B22, B23);                                     \
    DO_CHUNK(CBUF, 3, B30, B31, B32, B33);                                     \
    __syncthreads();                                                           \
  } while (0)

  // prologue: A(tile TW(0)) -> buf0, A(TW(1)) held in Q
  GLOAD(TW(0), P);
  DSWRITE(buf0, P);
  GLOAD(TW(1), Q);
  __syncthreads();

#pragma unroll 1
  for (int tq = 0; tq < 48; tq += 2) {
    TILE(tq, buf0, buf1, Q, P);      // even: compute buf0, commit A(tq+1), load A(tq+2)->P
    TILE(tq + 1, buf1, buf0, P, Q);  // odd : compute buf1, commit A(tq+2), load A(tq+3)->Q
  }
#undef TILE
#undef DO_CHUNK
#undef DSWRITE
#undef GLOAD
#undef TOFF
#undef TW

  // cross-wave reduce + tanh (red aliases lds; compute is done)
  float* red = lds;
#pragma unroll
  for (int q = 0; q < 4; ++q) {
    red[w * 1024 + (lk * 4 + q) * 64 + 0 + lrow] = acc0[q];
    red[w * 1024 + (lk * 4 + q) * 64 + 16 + lrow] = acc1[q];
    red[w * 1024 + (lk * 4 + q) * 64 + 32 + lrow] = acc2[q];
    red[w * 1024 + (lk * 4 + q) * 64 + 48 + lrow] = acc3[q];
  }
  __syncthreads();
#pragma unroll
  for (int idx = tid; idx < 1024; idx += 256) {
    const float s = red[idx] + red[1024 + idx] + red[2048 + idx] + red[3072 + idx];
    out[(size_t)mb * 1024 + idx] = tanhf(s);
  }
}

__global__ __launch_bounds__(256) void fill_sentinel(float* __restrict__ dst) {
  dst[blockIdx.x * 256 + threadIdx.x] = 7.0f;
}

extern "C" void kernel_launch(void* const* d_in, const int* in_sizes, int n_in,
                              void* d_out, int out_size, void* d_ws, size_t ws_size,
                              hipStream_t stream) {
  const float* x   = (const float*)d_in[0];
  const float* adj = (const float*)d_in[1];
  const float* W1  = (const float*)d_in[2];
  const float* b1  = (const float*)d_in[3];
  const float* W2  = (const float*)d_in[4];
  const float* b2  = (const float*)d_in[5];
  float* out = (float*)d_out;

  const size_t HBF_B = (size_t)3 * 8192 * 64 * 2;  // 3 MB
  const size_t T_B   = (size_t)8192 * 64 * 4;      // 2 MB
  if (ws_size < HBF_B + T_B) {
    fill_sentinel<<<2048, 256, 0, stream>>>(out);
    return;
  }
  unsigned short* hbf = (unsigned short*)d_ws;
  float* t = (float*)((char*)d_ws + HBF_B);

  // layer 1
  prep<<<3 * 256, 256, 0, stream>>>(x, W1, b1, hbf);
  gemm_mfma<<<512, 256, 0, stream>>>(adj, hbf, t);
  // layer 2
  prep<<<3 * 256, 256, 0, stream>>>(t, W2, b2, hbf);
  gemm_mfma<<<512, 256, 0, stream>>>(adj, hbf, out);
}

// Round 14
// 342.273 us; speedup vs baseline: 1.1927x; 1.0139x over previous
//
#include <hip/hip_runtime.h>

// RelGCN round 14: fp8-e4m3 adj cache. gemm1 (bf16 path, r13-verified) fuses
// adj->fp8 conversion into its staging regs and nt-streams a 192MiB copy;
// gemm2 reads 201MB instead of 805MB (total traffic 1610->1207 MB).
//   prep  : hbf = bf16(in@W1+b1) swizzled          (r13, verified)
//   gemm1 : t = tanh(sum adj_f32 @ hbf) + emit adjf8 = e4m3(adj*8192)
//   prep2 : h2f8 = e4m3(16*(t@W2+b2)) swizzled
//   probe : 1-block fp8 MFMA canary (sleep +508us iff fragment-layout bug)
//   gemm2 : out = tanh( (sum adjf8 @ h2f8) / 131072 )   [fp8 MFMA]

#define NN 8192
#define TS 516   // f32 LDS row stride (gemm1)
#define AS8 528  // fp8 LDS row stride in bytes (gemm2)

typedef __attribute__((ext_vector_type(4))) float float4v;
typedef __attribute__((ext_vector_type(8))) short short8v;
typedef __attribute__((ext_vector_type(4))) unsigned int uint4v;

__device__ inline unsigned short f2bf(float f) {
  unsigned int u = __builtin_bit_cast(unsigned int, f);
  return (unsigned short)((u + 0x7FFFu + ((u >> 16) & 1u)) >> 16);  // RNE
}

#if defined(__has_builtin)
#if __has_builtin(__builtin_amdgcn_cvt_pk_fp8_f32) && __has_builtin(__builtin_amdgcn_cvt_f32_fp8)
#define HW_FP8 1
#endif
#endif

__device__ inline unsigned char enc_fp8_sw(float x) {  // OCP e4m3fn, RNE
  unsigned int u = __builtin_bit_cast(unsigned int, x);
  unsigned int s = (u >> 24) & 0x80u;
  unsigned int a = u & 0x7fffffffu;
  if (a >= 0x43e00000u) return (unsigned char)(s | 0x7Eu);  // clamp 448
  int e = (int)(a >> 23) - 127;
  unsigned int enc;
  if (e >= -6) {
    unsigned int keep = (a >> 20) & 7u;
    unsigned int rem = a & 0xfffffu;
    unsigned int inc = (rem > 0x80000u) || (rem == 0x80000u && (keep & 1u));
    enc = (((unsigned)(e + 7) << 3) | keep) + inc;  // carry rolls exponent
  } else {
    float af = __builtin_bit_cast(float, a);
    enc = (unsigned int)(af * 512.0f + 0.5f);  // subnormal, m in 0..8
  }
  return (unsigned char)(s | enc);
}
__device__ inline float dec_fp8_sw(unsigned char b) {
  int E = (b >> 3) & 15, m = b & 7;
  float v = E ? ldexpf((float)(8 + m), E - 10) : ldexpf((float)m, -9);
  return (b & 0x80) ? -v : v;
}
__device__ inline unsigned int pk4_fp8(float a, float b, float c, float d) {
#ifdef HW_FP8
  int w = __builtin_amdgcn_cvt_pk_fp8_f32(a, b, 0, false);
  w = __builtin_amdgcn_cvt_pk_fp8_f32(c, d, w, true);
  return (unsigned int)w;
#else
  return (unsigned int)enc_fp8_sw(a) | ((unsigned int)enc_fp8_sw(b) << 8) |
         ((unsigned int)enc_fp8_sw(c) << 16) | ((unsigned int)enc_fp8_sw(d) << 24);
#endif
}
__device__ inline float dec_fp8(unsigned char v) {
#ifdef HW_FP8
  return __builtin_amdgcn_cvt_f32_fp8((int)v, 0);
#else
  return dec_fp8_sw(v);
#endif
}

// ---------------- prep (layer 1, bf16 swizzled; r13 verified) ----------------
__global__ __launch_bounds__(256) void prep(
    const float* __restrict__ in, const float* __restrict__ W,
    const float* __restrict__ b, unsigned short* __restrict__ hbf) {
  __shared__ float Ws[64 * 64];
  const int tid = threadIdx.x;
  const int r = blockIdx.x >> 8;
  const int g = blockIdx.x & 255;
  const int ml = tid >> 3;
  const int j0 = (tid & 7) * 8;
  const int m = g * 32 + ml;
#pragma unroll
  for (int i = 0; i < 16; ++i) Ws[tid + i * 256] = W[r * 4096 + tid + i * 256];
  float4v xr[16];
#pragma unroll
  for (int i = 0; i < 16; ++i) xr[i] = *(const float4v*)&in[(size_t)m * 64 + i * 4];
  float acc[8];
  {
    const float4v b0 = *(const float4v*)&b[r * 64 + j0];
    const float4v b1 = *(const float4v*)&b[r * 64 + j0 + 4];
#pragma unroll
    for (int jj = 0; jj < 4; ++jj) { acc[jj] = b0[jj]; acc[jj + 4] = b1[jj]; }
  }
  __syncthreads();
#pragma unroll
  for (int fi = 0; fi < 16; ++fi) {
    const float4v xv = xr[fi];
#pragma unroll
    for (int df = 0; df < 4; ++df) {
      const int f = fi * 4 + df;
      const float a = xv[df];
      const float4v w0 = *(const float4v*)&Ws[f * 64 + j0];
      const float4v w1 = *(const float4v*)&Ws[f * 64 + j0 + 4];
#pragma unroll
      for (int jj = 0; jj < 4; ++jj) {
        acc[jj] += a * w0[jj];
        acc[jj + 4] += a * w1[jj];
      }
    }
  }
  const size_t base = ((size_t)(r * 1024 + (m >> 3)) * 64) * 8 + (m & 7);
#pragma unroll
  for (int jj = 0; jj < 8; ++jj)
    hbf[base + (size_t)(j0 + jj) * 8] = f2bf(acc[jj]);
}

// ------------- prep2 (layer 2, fp8 swizzled, scale x16) -------------
__global__ __launch_bounds__(256) void prep2(
    const float* __restrict__ in, const float* __restrict__ W,
    const float* __restrict__ b, unsigned char* __restrict__ h2f8) {
  __shared__ float Ws[64 * 64];
  const int tid = threadIdx.x;
  const int r = blockIdx.x >> 8;
  const int g = blockIdx.x & 255;
  const int ml = tid >> 3;
  const int j0 = (tid & 7) * 8;
  const int m = g * 32 + ml;
#pragma unroll
  for (int i = 0; i < 16; ++i) Ws[tid + i * 256] = W[r * 4096 + tid + i * 256];
  float4v xr[16];
#pragma unroll
  for (int i = 0; i < 16; ++i) xr[i] = *(const float4v*)&in[(size_t)m * 64 + i * 4];
  float acc[8];
  {
    const float4v b0 = *(const float4v*)&b[r * 64 + j0];
    const float4v b1 = *(const float4v*)&b[r * 64 + j0 + 4];
#pragma unroll
    for (int jj = 0; jj < 4; ++jj) { acc[jj] = b0[jj]; acc[jj + 4] = b1[jj]; }
  }
  __syncthreads();
#pragma unroll
  for (int fi = 0; fi < 16; ++fi) {
    const float4v xv = xr[fi];
#pragma unroll
    for (int df = 0; df < 4; ++df) {
      const int f = fi * 4 + df;
      const float a = xv[df];
      const float4v w0 = *(const float4v*)&Ws[f * 64 + j0];
      const float4v w1 = *(const float4v*)&Ws[f * 64 + j0 + 4];
#pragma unroll
      for (int jj = 0; jj < 4; ++jj) {
        acc[jj] += a * w0[jj];
        acc[jj + 4] += a * w1[jj];
      }
    }
  }
  const unsigned int u0 = pk4_fp8(acc[0] * 16.f, acc[1] * 16.f, acc[2] * 16.f, acc[3] * 16.f);
  const unsigned int u1 = pk4_fp8(acc[4] * 16.f, acc[5] * 16.f, acc[6] * 16.f, acc[7] * 16.f);
  const size_t base = (size_t)(r * 1024 + (m >> 3)) * 512 + (m & 7);
#pragma unroll
  for (int jj = 0; jj < 4; ++jj) {
    h2f8[base + (size_t)(j0 + jj) * 8] = (unsigned char)((u0 >> (8 * jj)) & 0xff);
    h2f8[base + (size_t)(j0 + 4 + jj) * 8] = (unsigned char)((u1 >> (8 * jj)) & 0xff);
  }
}

// ------------- gemm1: bf16 MFMA (r13 verified) + adjf8 emission -------------
__global__ __launch_bounds__(256) void gemm_mfma(
    const float* __restrict__ adj, const unsigned short* __restrict__ hbf,
    float* __restrict__ out, unsigned char* __restrict__ adjf8) {
  __shared__ float lds[2 * 16 * TS];
  float* buf0 = lds;
  float* buf1 = lds + 16 * TS;
  const int tid = threadIdx.x;
  const int w = tid >> 6;
  const int l = tid & 63;
  const int lrow = l & 15;
  const int lk = l >> 4;
  const int mb = blockIdx.x;
  const int phase = (mb * 29) % 48;
  const int srow = tid >> 4;
  const int sseg = tid & 15;
  const float* arow = adj + (size_t)(mb * 16 + srow) * NN + sseg * 4;
  unsigned char* a8row = adjf8 + (size_t)(mb * 16 + srow) * NN + sseg * 4;

  float4v acc0 = {0.f, 0.f, 0.f, 0.f}, acc1 = acc0, acc2 = acc0, acc3 = acc0;
  float4v P0, P1, P2, P3, P4, P5, P6, P7, Q0, Q1, Q2, Q3, Q4, Q5, Q6, Q7;

#define TW(TQ) ((TQ) + phase >= 48 ? (TQ) + phase - 48 : (TQ) + phase)
#define TOFF(T) (((size_t)((T) >> 4) << 26) + ((size_t)((T) & 15) << 9))

#define GLOAD(T, S)                                                            \
  do {                                                                         \
    const float* pa_ = arow + TOFF(T);                                         \
    S##0 = __builtin_nontemporal_load((const float4v*)(pa_));                  \
    S##1 = __builtin_nontemporal_load((const float4v*)(pa_ + 64));             \
    S##2 = __builtin_nontemporal_load((const float4v*)(pa_ + 128));            \
    S##3 = __builtin_nontemporal_load((const float4v*)(pa_ + 192));            \
    S##4 = __builtin_nontemporal_load((const float4v*)(pa_ + 256));            \
    S##5 = __builtin_nontemporal_load((const float4v*)(pa_ + 320));            \
    S##6 = __builtin_nontemporal_load((const float4v*)(pa_ + 384));            \
    S##7 = __builtin_nontemporal_load((const float4v*)(pa_ + 448));            \
  } while (0)

#define F8ST(S, I)                                                             \
  __builtin_nontemporal_store(                                                 \
      pk4_fp8(S[0] * 8192.f, S[1] * 8192.f, S[2] * 8192.f, S[3] * 8192.f),     \
      (unsigned int*)(p8_ + (I)*64))

#define DSWRITE(BUF, S, T)                                                     \
  do {                                                                         \
    float* p_ = (BUF) + srow * TS + sseg * 4;                                  \
    *(float4v*)(p_) = S##0;                                                    \
    *(float4v*)(p_ + 64) = S##1;                                               \
    *(float4v*)(p_ + 128) = S##2;                                              \
    *(float4v*)(p_ + 192) = S##3;                                              \
    *(float4v*)(p_ + 256) = S##4;                                              \
    *(float4v*)(p_ + 320) = S##5;                                              \
    *(float4v*)(p_ + 384) = S##6;                                              \
    *(float4v*)(p_ + 448) = S##7;                                              \
    unsigned char* p8_ = a8row + TOFF(T);                                      \
    F8ST(S##0, 0); F8ST(S##1, 1); F8ST(S##2, 2); F8ST(S##3, 3);                \
    F8ST(S##4, 4); F8ST(S##5, 5); F8ST(S##6, 6); F8ST(S##7, 7);                \
  } while (0)

#define DO_CHUNK(CUR, CC, B0, B1, B2, B3)                                      \
  do {                                                                         \
    const float* ap_ = (CUR) + lrow * TS + (w * 4 + (CC)) * 32 + lk * 8;       \
    const float4v a0_ = *(const float4v*)ap_;                                  \
    const float4v a1_ = *(const float4v*)(ap_ + 4);                            \
    short8v av_;                                                               \
    av_[0] = (short)f2bf(a0_[0]); av_[1] = (short)f2bf(a0_[1]);                \
    av_[2] = (short)f2bf(a0_[2]); av_[3] = (short)f2bf(a0_[3]);                \
    av_[4] = (short)f2bf(a1_[0]); av_[5] = (short)f2bf(a1_[1]);                \
    av_[6] = (short)f2bf(a1_[2]); av_[7] = (short)f2bf(a1_[3]);                \
    acc0 = __builtin_amdgcn_mfma_f32_16x16x32_bf16(av_, B0, acc0, 0, 0, 0);    \
    acc1 = __builtin_amdgcn_mfma_f32_16x16x32_bf16(av_, B1, acc1, 0, 0, 0);    \
    acc2 = __builtin_amdgcn_mfma_f32_16x16x32_bf16(av_, B2, acc2, 0, 0, 0);    \
    acc3 = __builtin_amdgcn_mfma_f32_16x16x32_bf16(av_, B3, acc3, 0, 0, 0);    \
  } while (0)

#define TILE(TQ, CBUF, WBUF, WS, LS)                                           \
  do {                                                                         \
    const int T_ = TW(TQ);                                                     \
    const unsigned short* pbb_ =                                               \
        hbf +                                                                  \
        ((size_t)((T_ >> 4) * 1024 + (T_ & 15) * 64 + w * 16 + lk) * 512) +    \
        lrow * 8;                                                              \
    const short8v B00 = *(const short8v*)(pbb_);                               \
    const short8v B01 = *(const short8v*)(pbb_ + 128);                         \
    const short8v B02 = *(const short8v*)(pbb_ + 256);                         \
    const short8v B03 = *(const short8v*)(pbb_ + 384);                         \
    const short8v B10 = *(const short8v*)(pbb_ + 2048);                        \
    const short8v B11 = *(const short8v*)(pbb_ + 2176);                        \
    const short8v B12 = *(const short8v*)(pbb_ + 2304);                        \
    const short8v B13 = *(const short8v*)(pbb_ + 2432);                        \
    const short8v B20 = *(const short8v*)(pbb_ + 4096);                        \
    const short8v B21 = *(const short8v*)(pbb_ + 4224);                        \
    const short8v B22 = *(const short8v*)(pbb_ + 4352);                        \
    const short8v B23 = *(const short8v*)(pbb_ + 4480);                        \
    const short8v B30 = *(const short8v*)(pbb_ + 6144);                        \
    const short8v B31 = *(const short8v*)(pbb_ + 6272);                        \
    const short8v B32 = *(const short8v*)(pbb_ + 6400);                        \
    const short8v B33 = *(const short8v*)(pbb_ + 6528);                        \
    if ((TQ) + 1 < 48) DSWRITE(WBUF, WS, TW((TQ) + 1));                        \
    if ((TQ) + 2 < 48) GLOAD(TW((TQ) + 2), LS);                                \
    DO_CHUNK(CBUF, 0, B00, B01, B02, B03);                                     \
    DO_CHUNK(CBUF, 1, B10, B11, B12, B13);                                     \
    DO_CHUNK(CBUF, 2, B20, B21, B22, B23);                                     \
    DO_CHUNK(CBUF, 3, B30, B31, B32, B33);                                     \
    __syncthreads();                                                           \
  } while (0)

  GLOAD(TW(0), P);
  DSWRITE(buf0, P, TW(0));
  GLOAD(TW(1), Q);
  __syncthreads();

#pragma unroll 1
  for (int tq = 0; tq < 48; tq += 2) {
    TILE(tq, buf0, buf1, Q, P);
    TILE(tq + 1, buf1, buf0, P, Q);
  }
#undef TILE
#undef DO_CHUNK
#undef DSWRITE
#undef F8ST
#undef GLOAD
#undef TW

  float* red = lds;
#pragma unroll
  for (int q = 0; q < 4; ++q) {
    red[w * 1024 + (lk * 4 + q) * 64 + 0 + lrow] = acc0[q];
    red[w * 1024 + (lk * 4 + q) * 64 + 16 + lrow] = acc1[q];
    red[w * 1024 + (lk * 4 + q) * 64 + 32 + lrow] = acc2[q];
    red[w * 1024 + (lk * 4 + q) * 64 + 48 + lrow] = acc3[q];
  }
  __syncthreads();
#pragma unroll
  for (int idx = tid; idx < 1024; idx += 256) {
    const float s = red[idx] + red[1024 + idx] + red[2048 + idx] + red[3072 + idx];
    out[(size_t)mb * 1024 + idx] = tanhf(s);
  }
}

// ------------- gemm2: fp8 MFMA on cached adjf8 (201 MB read) -------------
__global__ __launch_bounds__(256) void gemm_fp8(
    const unsigned char* __restrict__ adjf8, const unsigned char* __restrict__ h2f8,
    float* __restrict__ out) {
  __shared__ __attribute__((aligned(16))) unsigned char lds8[2 * 16 * AS8];
  unsigned char* buf0 = lds8;
  unsigned char* buf1 = lds8 + 16 * AS8;
  const int tid = threadIdx.x;
  const int w = tid >> 6;
  const int l = tid & 63;
  const int lrow = l & 15;
  const int lk = l >> 4;
  const int mb = blockIdx.x;
  const int phase = (mb * 29) % 48;
  const int srow = tid >> 4;
  const int sseg = tid & 15;
  const unsigned char* arow = adjf8 + (size_t)(mb * 16 + srow) * NN + sseg * 32;

  float4v acc0 = {0.f, 0.f, 0.f, 0.f}, acc1 = acc0, acc2 = acc0, acc3 = acc0;
  uint4v Pa, Pb, Qa, Qb;

#define TW(TQ) ((TQ) + phase >= 48 ? (TQ) + phase - 48 : (TQ) + phase)

#define GLOAD8(T, SA, SB)                                                      \
  do {                                                                         \
    const unsigned char* pa_ = arow + TOFF(T);                                 \
    SA = __builtin_nontemporal_load((const uint4v*)(pa_));                     \
    SB = __builtin_nontemporal_load((const uint4v*)(pa_ + 16));                \
  } while (0)

#define DSWRITE8(BUF, SA, SB)                                                  \
  do {                                                                         \
    unsigned char* p_ = (BUF) + srow * AS8 + sseg * 32;                        \
    *(uint4v*)(p_) = SA;                                                       \
    *(uint4v*)(p_ + 16) = SB;                                                  \
  } while (0)

#define DO_CHUNK8(CUR, CC, B0, B1, B2, B3)                                     \
  do {                                                                         \
    const long av_ =                                                           \
        *(const long*)&(CUR)[lrow * AS8 + (w * 4 + (CC)) * 32 + lk * 8];       \
    acc0 = __builtin_amdgcn_mfma_f32_16x16x32_fp8_fp8(av_, B0, acc0, 0, 0, 0); \
    acc1 = __builtin_amdgcn_mfma_f32_16x16x32_fp8_fp8(av_, B1, acc1, 0, 0, 0); \
    acc2 = __builtin_amdgcn_mfma_f32_16x16x32_fp8_fp8(av_, B2, acc2, 0, 0, 0); \
    acc3 = __builtin_amdgcn_mfma_f32_16x16x32_fp8_fp8(av_, B3, acc3, 0, 0, 0); \
  } while (0)

#define TILE8(TQ, CBUF, WBUF, WSA, WSB, LSA, LSB)                              \
  do {                                                                         \
    const int T_ = TW(TQ);                                                     \
    const unsigned char* pbb_ =                                                \
        h2f8 +                                                                 \
        ((size_t)((T_ >> 4) * 1024 + (T_ & 15) * 64 + w * 16 + lk) * 512) +    \
        lrow * 8;                                                              \
    const long B00 = *(const long*)(pbb_);                                     \
    const long B01 = *(const long*)(pbb_ + 128);                               \
    const long B02 = *(const long*)(pbb_ + 256);                               \
    const long B03 = *(const long*)(pbb_ + 384);                               \
    const long B10 = *(const long*)(pbb_ + 2048);                              \
    const long B11 = *(const long*)(pbb_ + 2176);                              \
    const long B12 = *(const long*)(pbb_ + 2304);                              \
    const long B13 = *(const long*)(pbb_ + 2432);                              \
    const long B20 = *(const long*)(pbb_ + 4096);                              \
    const long B21 = *(const long*)(pbb_ + 4224);                              \
    const long B22 = *(const long*)(pbb_ + 4352);                              \
    const long B23 = *(const long*)(pbb_ + 4480);                              \
    const long B30 = *(const long*)(pbb_ + 6144);                              \
    const long B31 = *(const long*)(pbb_ + 6272);                              \
    const long B32 = *(const long*)(pbb_ + 6400);                              \
    const long B33 = *(const long*)(pbb_ + 6528);                              \
    if ((TQ) + 1 < 48) DSWRITE8(WBUF, WSA, WSB);                               \
    if ((TQ) + 2 < 48) GLOAD8(TW((TQ) + 2), LSA, LSB);                         \
    DO_CHUNK8(CBUF, 0, B00, B01, B02, B03);                                    \
    DO_CHUNK8(CBUF, 1, B10, B11, B12, B13);                                    \
    DO_CHUNK8(CBUF, 2, B20, B21, B22, B23);                                    \
    DO_CHUNK8(CBUF, 3, B30, B31, B32, B33);                                    \
    __syncthreads();                                                           \
  } while (0)

  GLOAD8(TW(0), Pa, Pb);
  DSWRITE8(buf0, Pa, Pb);
  GLOAD8(TW(1), Qa, Qb);
  __syncthreads();

#pragma unroll 1
  for (int tq = 0; tq < 48; tq += 2) {
    TILE8(tq, buf0, buf1, Qa, Qb, Pa, Pb);
    TILE8(tq + 1, buf1, buf0, Pa, Pb, Qa, Qb);
  }
#undef TILE8
#undef DO_CHUNK8
#undef DSWRITE8
#undef GLOAD8
#undef TW

  float* red = (float*)lds8;
#pragma unroll
  for (int q = 0; q < 4; ++q) {
    red[w * 1024 + (lk * 4 + q) * 64 + 0 + lrow] = acc0[q];
    red[w * 1024 + (lk * 4 + q) * 64 + 16 + lrow] = acc1[q];
    red[w * 1024 + (lk * 4 + q) * 64 + 32 + lrow] = acc2[q];
    red[w * 1024 + (lk * 4 + q) * 64 + 48 + lrow] = acc3[q];
  }
  __syncthreads();
#pragma unroll
  for (int idx = tid; idx < 1024; idx += 256) {
    const float s = red[idx] + red[1024 + idx] + red[2048 + idx] + red[3072 + idx];
    out[(size_t)mb * 1024 + idx] = tanhf(s * (1.0f / 131072.0f));
  }
}

// ------------- fp8 canary: +508us sleep iff fragment layout wrong -------------
__global__ __launch_bounds__(64) void fp8_probe(
    const unsigned char* __restrict__ adjf8, const unsigned char* __restrict__ h2f8) {
  __shared__ float cm[16 * 64];
  __shared__ int flag;
  const int l = threadIdx.x;
  if (l == 0) flag = 0;
  const int lrow = l & 15, lk = l >> 4;
  float4v acc[4];
#pragma unroll
  for (int g = 0; g < 4; ++g) acc[g] = (float4v){0.f, 0.f, 0.f, 0.f};
#pragma unroll
  for (int c = 0; c < 4; ++c) {  // K = 128, relation 0, rows 0..15
    const long av = *(const long*)&adjf8[(size_t)lrow * NN + c * 32 + lk * 8];
#pragma unroll
    for (int g = 0; g < 4; ++g) {
      const long bv =
          *(const long*)&h2f8[(size_t)(c * 4 + lk) * 512 + (g * 16 + lrow) * 8];
      acc[g] = __builtin_amdgcn_mfma_f32_16x16x32_fp8_fp8(av, bv, acc[g], 0, 0, 0);
    }
  }
#pragma unroll
  for (int g = 0; g < 4; ++g)
#pragma unroll
    for (int q = 0; q < 4; ++q)
      cm[(lk * 4 + q) * 64 + g * 16 + lrow] = acc[g][q];
  __syncthreads();
  const int row = l & 15, c0 = (l >> 4) * 16;
  float maxd = 0.f;
  for (int cc = 0; cc < 16; ++cc) {
    const int col = c0 + cc;
    float ref = 0.f;
    for (int k = 0; k < 128; ++k)
      ref += dec_fp8(adjf8[(size_t)row * NN + k]) *
             dec_fp8(h2f8[(size_t)(k >> 3) * 512 + col * 8 + (k & 7)]);
    maxd = fmaxf(maxd, fabsf(cm[row * 64 + col] - ref));
  }
  if (maxd > 0.05f) atomicOr(&flag, 1);
  __syncthreads();
  if (flag) {
    for (int i = 0; i < 150; ++i) __builtin_amdgcn_s_sleep(127);
  }
}

__global__ __launch_bounds__(256) void fill_sentinel(float* __restrict__ dst) {
  dst[blockIdx.x * 256 + threadIdx.x] = 7.0f;
}

extern "C" void kernel_launch(void* const* d_in, const int* in_sizes, int n_in,
                              void* d_out, int out_size, void* d_ws, size_t ws_size,
                              hipStream_t stream) {
  const float* x   = (const float*)d_in[0];
  const float* adj = (const float*)d_in[1];
  const float* W1  = (const float*)d_in[2];
  const float* b1  = (const float*)d_in[3];
  const float* W2  = (const float*)d_in[4];
  const float* b2  = (const float*)d_in[5];
  float* out = (float*)d_out;

  const size_t HBF_B = (size_t)3 * 8192 * 64 * 2;        // 3 MB
  const size_t T_B   = (size_t)8192 * 64 * 4;            // 2 MB
  const size_t H2_B  = (size_t)3 * 8192 * 64;            // 1.5 MB
  const size_t A8_B  = (size_t)3 * 8192 * 8192;          // 192 MiB
  if (ws_size < HBF_B + T_B + H2_B + A8_B) {
    fill_sentinel<<<2048, 256, 0, stream>>>(out);
    return;
  }
  unsigned short* hbf  = (unsigned short*)d_ws;
  float* t             = (float*)((char*)d_ws + HBF_B);
  unsigned char* h2f8  = (unsigned char*)((char*)d_ws + HBF_B + T_B);
  unsigned char* adjf8 = (unsigned char*)((char*)d_ws + HBF_B + T_B + H2_B);

  // layer 1 (bf16 path, verified) + adjf8 emission
  prep<<<3 * 256, 256, 0, stream>>>(x, W1, b1, hbf);
  gemm_mfma<<<512, 256, 0, stream>>>(adj, hbf, t, adjf8);
  // layer 2 (fp8 path, 201 MB adj read)
  prep2<<<3 * 256, 256, 0, stream>>>(t, W2, b2, h2f8);
  fp8_probe<<<1, 64, 0, stream>>>(adjf8, h2f8);  // canary
  gemm_fp8<<<512, 256, 0, stream>>>(adjf8, h2f8, out);
}